// Round 7
// baseline (1343.700 us; speedup 1.0000x reference)
//
#include <hip/hip_runtime.h>
#include <hip/hip_bf16.h>
#include <math.h>

#define HID 128
#define NH  4
#define HD  32
#define FFD 512
#define RR  8
#define SCAN_B 1024

typedef __attribute__((ext_vector_type(8))) short bf16x8;
typedef __attribute__((ext_vector_type(4))) float f32x4;
typedef unsigned short u16;

static __device__ __forceinline__ float bf2f(u16 u) {
    union { unsigned int i; float f; } v; v.i = ((unsigned int)u) << 16; return v.f;
}
static __device__ __forceinline__ u16 f2bf(float f) {
    union { float f; unsigned int i; } v; v.f = f;
    unsigned int x = v.i;
    return (u16)((x + 0x7fffu + ((x >> 16) & 1u)) >> 16);
}

__global__ void zeroout_kernel(float* out, int n) {
    int i = blockIdx.x * 256 + threadIdx.x;
    if (i < n) out[i] = 0.f;
}

__global__ void init_kernel(float* acc, int* deg, int NN) {
    int i = blockIdx.x * 256 + threadIdx.x;
    if (i < NN * HID) acc[i] = 0.f;
    if (i < NN) deg[i] = 0;
}

// ---------------------------------------------------------------------------
// Per-row LayerNorm stats (fp32 input).
// ---------------------------------------------------------------------------
__global__ void stats_kernel(const float* in, float* mu, float* rs, int NN) {
    int row = blockIdx.x * 4 + (threadIdx.x >> 6);
    int lane = threadIdx.x & 63;
    if (row >= NN) return;
    const float* p = in + (size_t)row * HID;
    float v0 = p[lane], v1 = p[lane + 64];
    float s = v0 + v1;
    #pragma unroll
    for (int o = 32; o > 0; o >>= 1) s += __shfl_xor(s, o, 64);
    float m = s * (1.0f / HID);
    float d0 = v0 - m, d1 = v1 - m;
    float q = d0 * d0 + d1 * d1;
    #pragma unroll
    for (int o = 32; o > 0; o >>= 1) q += __shfl_xor(q, o, 64);
    if (lane == 0) { mu[row] = m; rs[row] = rsqrtf(q * (1.0f / HID) + 1e-5f); }
}

// ---------------------------------------------------------------------------
// Transpose fp32 weights to bf16 [n][k] for contiguous GEMM B-fragments.
// ---------------------------------------------------------------------------
__global__ void transpose_kernel(const float* w, const float* rootw,
                                 const float* w1, const float* w2,
                                 u16* WT, u16* rootT, u16* W1T, u16* W2T, int R) {
    int i = blockIdx.x * 256 + threadIdx.x;
    int nW = R * HID * HID;
    if (i < nW) {
        int r = i / (HID * HID); int rem = i % (HID * HID);
        int n = rem / HID, k = rem % HID;
        WT[i] = f2bf(w[r * HID * HID + k * HID + n]);
    } else if (i < nW + HID * HID) {
        int j = i - nW; int n = j / HID, k = j % HID;
        rootT[j] = f2bf(rootw[k * HID + n]);
    } else if (i < nW + HID * HID + FFD * HID) {
        int j = i - nW - HID * HID; int n = j / HID, k = j % HID;
        W1T[j] = f2bf(w1[k * FFD + n]);
    } else if (i < nW + HID * HID + FFD * HID + HID * FFD) {
        int j = i - nW - HID * HID - FFD * HID; int n = j / FFD, k = j % FFD;
        W2T[j] = f2bf(w2[k * HID + n]);
    }
}

__global__ void ae_kernel(const float* emb, const float* att_edge, float* ae, int R) {
    int i = threadIdx.x;
    if (i >= R * NH) return;
    int r = i >> 2, h = i & 3;
    float s = 0.f;
    #pragma unroll
    for (int d = 0; d < HD; d++)
        s += emb[r * HID + h * HD + d] * att_edge[h * HD + d];
    ae[i] = s;
}

// ---------------------------------------------------------------------------
// MFMA GEMM with fused LN on A and fused epilogues.  64x64 block tile,
// 4 waves, 16x16x32 bf16.  A frag: m=lane&15, k=quad*8+j;  B from BT[n][k];
// D: col=lane&15, row=quad*4+j.
// AM 0: A = fp32 + LN affine -> bf16      AM 2: A = bf16 raw
// EPI 0: raw bf16 store (x_chunk)
// EPI 1: + acc(normalized msg) + bias, elu, + x(fp32) -> FP32 store (d_out)
// EPI 2: + b1, exact gelu -> bf16 store (u)
// EPI 3: + b2 + resid(fp32) -> FP32 store in place (d_out)
// ---------------------------------------------------------------------------
template <int AM, int EPI>
__global__ __launch_bounds__(256)
void gemm_kernel(const void* Araw, const float* mu, const float* rs,
                 const float* lw, const float* lb,
                 const u16* BT, void* Cout, const float* bias,
                 const float* acc, const float* xin,
                 int M, int N, int K, int aOff, int cOff) {
    int w = threadIdx.x >> 6, lane = threadIdx.x & 63;
    int l15 = lane & 15, quad = lane >> 4;
    int m0 = blockIdx.x * 64 + w * 16;
    int n0 = blockIdx.y * 64;
    int rowA = m0 + l15; if (rowA > M - 1) rowA = M - 1;
    int gA = aOff + rowA;
    float muv = 0.f, rsv = 0.f;
    if (AM != 2) { muv = mu[gA]; rsv = rs[gA]; }

    f32x4 accr[4] = {};
    for (int kc = 0; kc < K; kc += 32) {
        bf16x8 a;
        if (AM == 0) {
            const float* ap = (const float*)Araw + (size_t)gA * K + quad * 8 + kc;
            float4 xa0 = *(const float4*)(ap);
            float4 xa1 = *(const float4*)(ap + 4);
            float4 w0 = *(const float4*)(lw + kc + quad * 8);
            float4 w1v = *(const float4*)(lw + kc + quad * 8 + 4);
            float4 b0 = *(const float4*)(lb + kc + quad * 8);
            float4 b1v = *(const float4*)(lb + kc + quad * 8 + 4);
            a[0] = (short)f2bf((xa0.x - muv) * rsv * w0.x + b0.x);
            a[1] = (short)f2bf((xa0.y - muv) * rsv * w0.y + b0.y);
            a[2] = (short)f2bf((xa0.z - muv) * rsv * w0.z + b0.z);
            a[3] = (short)f2bf((xa0.w - muv) * rsv * w0.w + b0.w);
            a[4] = (short)f2bf((xa1.x - muv) * rsv * w1v.x + b1v.x);
            a[5] = (short)f2bf((xa1.y - muv) * rsv * w1v.y + b1v.y);
            a[6] = (short)f2bf((xa1.z - muv) * rsv * w1v.z + b1v.z);
            a[7] = (short)f2bf((xa1.w - muv) * rsv * w1v.w + b1v.w);
        } else {
            const u16* ap = (const u16*)Araw + (size_t)gA * K + quad * 8 + kc;
            a = *(const bf16x8*)ap;
        }
        #pragma unroll
        for (int t = 0; t < 4; t++) {
            const u16* bp = BT + (size_t)(n0 + t * 16 + l15) * K + quad * 8 + kc;
            bf16x8 bfrag = *(const bf16x8*)bp;
            accr[t] = __builtin_amdgcn_mfma_f32_16x16x32_bf16(a, bfrag, accr[t], 0, 0, 0);
        }
    }
    #pragma unroll
    for (int t = 0; t < 4; t++) {
        int col = n0 + t * 16 + l15;
        #pragma unroll
        for (int j = 0; j < 4; j++) {
            int row = m0 + quad * 4 + j;
            if (row < M) {
                float v = accr[t][j];
                int grow = cOff + row;
                size_t off = (size_t)grow * N + col;
                if (EPI == 0) {
                    ((u16*)Cout)[off] = f2bf(v);
                } else if (EPI == 1) {
                    float msg = acc[(size_t)grow * HID + col];
                    float o = v + msg + bias[col];
                    o = o > 0.f ? o : expm1f(o);
                    ((float*)Cout)[off] = xin[off] + o;
                } else if (EPI == 2) {
                    v += bias[col];
                    v = 0.5f * v * (1.0f + erff(v * 0.70710678118654752f));
                    ((u16*)Cout)[off] = f2bf(v);
                } else {
                    ((float*)Cout)[off] = v + bias[col] + xin[off];
                }
            }
        }
    }
}

// ---------------------------------------------------------------------------
// Per-(node,head) dots of relation rc's projection with att_src / att_dst.
// ---------------------------------------------------------------------------
__global__ void dots_kernel(const u16* x_chunk, const float* att_src,
                            const float* att_dst, float* as_o, float* ad_o, int NN) {
    int idx = blockIdx.x * 256 + threadIdx.x;
    if (idx >= NN * NH) return;
    int h = idx & 3, n = idx >> 2;
    const u16* p = x_chunk + (size_t)n * HID + h * HD;
    float s = 0.f, t = 0.f;
    #pragma unroll
    for (int d = 0; d < HD; d++) {
        float xv = bf2f(p[d]);
        s += xv * att_src[h * HD + d];
        t += xv * att_dst[h * HD + d];
    }
    as_o[idx] = s; ad_o[idx] = t;
}

// ---------------------------------------------------------------------------
// CSR by dst: histogram -> 3-phase scan -> scatter packed (r<<24 | s).
// ---------------------------------------------------------------------------
__global__ void deg_kernel(const int* ei, int* deg, int E, int NN) {
    int e = blockIdx.x * 256 + threadIdx.x;
    if (e >= E) return;
    int d = ei[E + e];
    if ((unsigned)d < (unsigned)NN) atomicAdd(&deg[d], 1);
}

__global__ void scan1_kernel(const int* in, int* out, int* bsum, int n) {
    __shared__ int buf[SCAN_B];
    int i = blockIdx.x * SCAN_B + threadIdx.x;
    int v = (i < n) ? in[i] : 0;
    buf[threadIdx.x] = v;
    __syncthreads();
    for (int s = 1; s < SCAN_B; s <<= 1) {
        int t = (threadIdx.x >= s) ? buf[threadIdx.x - s] : 0;
        __syncthreads();
        buf[threadIdx.x] += t;
        __syncthreads();
    }
    if (i < n) out[i] = buf[threadIdx.x] - v;
    if (threadIdx.x == SCAN_B - 1) bsum[blockIdx.x] = buf[SCAN_B - 1];
}

__global__ void scan2_kernel(int* bsum, int nb) {
    __shared__ int buf[SCAN_B];
    int v = (threadIdx.x < nb) ? bsum[threadIdx.x] : 0;
    buf[threadIdx.x] = v;
    __syncthreads();
    for (int s = 1; s < SCAN_B; s <<= 1) {
        int t = (threadIdx.x >= s) ? buf[threadIdx.x - s] : 0;
        __syncthreads();
        buf[threadIdx.x] += t;
        __syncthreads();
    }
    if (threadIdx.x < nb) bsum[threadIdx.x] = buf[threadIdx.x] - v;
    if (threadIdx.x == SCAN_B - 1) bsum[nb] = buf[SCAN_B - 1];
}

__global__ void scan3_kernel(int* out, int* curpos, const int* bsum, int n, int nb) {
    int i = blockIdx.x * SCAN_B + threadIdx.x;
    if (i < n) {
        int o = out[i] + bsum[blockIdx.x];
        out[i] = o; curpos[i] = o;
    }
    if (i == 0) out[n] = bsum[nb];
}

__global__ void fill_kernel(const int* ei, const int* et, int* curpos,
                            int* rs_arr, int E, int NN) {
    int e = blockIdx.x * 256 + threadIdx.x;
    if (e >= E) return;
    int s = ei[e], d = ei[E + e], r = et[e];
    if ((unsigned)d >= (unsigned)NN) return;
    int pos = atomicAdd(&curpos[d], 1);
    if ((unsigned)pos < (unsigned)E)
        rs_arr[pos] = ((r & 255) << 24) | (s & 0xFFFFFF);
}

// ---------------------------------------------------------------------------
// Exact two-pass softmax weights per (dst node, head).
// ---------------------------------------------------------------------------
__global__ void wgt_kernel(const int* offs, const int* rs_arr,
                           const float* as_all, const float* ad_all, const float* ae,
                           float* wgt, int NN, int E) {
    int idx = blockIdx.x * 256 + threadIdx.x;
    if (idx >= NN * NH) return;
    int h = idx & 3, n = idx >> 2;
    int p0 = offs[n], p1 = offs[n + 1];
    if (p0 < 0) p0 = 0;
    if (p1 > E) p1 = E;
    if (p0 >= p1) return;
    float mx = -1e30f;
    for (int p = p0; p < p1; p++) {
        int v = rs_arr[p];
        int r = v >> 24, s = v & 0xFFFFFF;
        if (s >= NN || r >= RR) { wgt[(size_t)p * NH + h] = -1e30f; continue; }
        float a = as_all[((size_t)r * NN + s) * NH + h]
                + ad_all[((size_t)r * NN + n) * NH + h]
                + ae[r * NH + h];
        a = a > 0.f ? a : 0.2f * a;
        wgt[(size_t)p * NH + h] = a;
        mx = fmaxf(mx, a);
    }
    float dn = 0.f;
    for (int p = p0; p < p1; p++)
        dn += __expf(wgt[(size_t)p * NH + h] - mx);
    float inv = 1.0f / (dn + 1e-16f);
    for (int p = p0; p < p1; p++)
        wgt[(size_t)p * NH + h] = __expf(wgt[(size_t)p * NH + h] - mx) * inv;
}

// ---------------------------------------------------------------------------
// Message accumulation for relation rc.  One block (128 thr) per dst node.
// ---------------------------------------------------------------------------
__global__ void msg2_kernel(const int* offs, const int* rs_arr, const float* wgt,
                            const u16* x_chunk, float* acc, int rc, int NN, int E) {
    int n = blockIdx.x;
    int c = threadIdx.x, h = c >> 5;
    int p0 = offs[n], p1 = offs[n + 1];
    if (p0 < 0) p0 = 0;
    if (p1 > E) p1 = E;
    if (p0 >= p1) return;
    float av = acc[(size_t)n * HID + c];
    for (int p = p0; p < p1; p++) {
        int v = rs_arr[p];
        if ((v >> 24) != rc) continue;
        int s = v & 0xFFFFFF;
        if (s >= NN) continue;
        av += wgt[(size_t)p * NH + h] * bf2f(x_chunk[(size_t)s * HID + c]);
    }
    acc[(size_t)n * HID + c] = av;
}

// ---------------------------------------------------------------------------
extern "C" void kernel_launch(void* const* d_in, const int* in_sizes, int n_in,
                              void* d_out, int out_size, void* d_ws, size_t ws_size,
                              hipStream_t stream) {
    const float* x        = (const float*)d_in[0];
    const float* w        = (const float*)d_in[1];
    const float* rootw    = (const float*)d_in[2];
    const float* emb      = (const float*)d_in[3];
    const float* att_src  = (const float*)d_in[4];
    const float* att_dst  = (const float*)d_in[5];
    const float* att_edge = (const float*)d_in[6];
    const float* bias     = (const float*)d_in[7];
    const float* n1w      = (const float*)d_in[8];
    const float* n1b      = (const float*)d_in[9];
    const float* n2w      = (const float*)d_in[10];
    const float* n2b      = (const float*)d_in[11];
    const float* w1       = (const float*)d_in[12];
    const float* b1       = (const float*)d_in[13];
    const float* w2       = (const float*)d_in[14];
    const float* b2       = (const float*)d_in[15];
    const int* ei = (const int*)d_in[16];
    const int* et = (const int*)d_in[17];

    int NN = in_sizes[0] / HID;         // 50000
    int R  = in_sizes[1] / (HID * HID); // 8
    int E  = in_sizes[17];              // 800000

    // ---- arena (~70 MiB; R5 proved ws_size covers it) ---------------------
    char* p = (char*)d_ws;
    auto alloc = [&](size_t bytes) -> char* {
        char* q = p; p += (bytes + 255) & ~(size_t)255; return q;
    };
    int* offs    = (int*)alloc((size_t)(NN + 1) * 4);
    int* deg     = (int*)alloc((size_t)NN * 4);
    int* curpos  = (int*)alloc((size_t)NN * 4);
    int nbScan = (NN + SCAN_B - 1) / SCAN_B;
    int* bsum    = (int*)alloc((size_t)(nbScan + 1) * 4);
    int* rs_arr  = (int*)alloc((size_t)E * 4);
    u16* WTw   = (u16*)alloc((size_t)R * HID * HID * 2);
    u16* rootT = (u16*)alloc((size_t)HID * HID * 2);
    u16* W1T   = (u16*)alloc((size_t)FFD * HID * 2);
    u16* W2T   = (u16*)alloc((size_t)HID * FFD * 2);
    float* ae  = (float*)alloc((size_t)R * NH * 4);
    float* mu1 = (float*)alloc((size_t)NN * 4);
    float* rs1 = (float*)alloc((size_t)NN * 4);
    float* mu2 = (float*)alloc((size_t)NN * 4);
    float* rs2 = (float*)alloc((size_t)NN * 4);
    float* as_all = (float*)alloc((size_t)R * NN * NH * 4);
    float* ad_all = (float*)alloc((size_t)R * NN * NH * 4);
    float* wgt    = (float*)alloc((size_t)E * NH * 4);
    float* acc    = (float*)alloc((size_t)NN * HID * 4);
    u16* x_chunk  = (u16*)alloc((size_t)NN * HID * 2);
    u16* u_ch = x_chunk;              // alias: FFN intermediate (x_chunk dead then)
    float* x2 = (float*)d_out;        // x2 lives in d_out (fp32) until FFN2 overwrites

    size_t used = (size_t)(p - (char*)d_ws);
    if (used > ws_size) {
        zeroout_kernel<<<(out_size + 255) / 256, 256, 0, stream>>>((float*)d_out, out_size);
        return;
    }

    // ---- phase 0: init, stats, weights, CSR -------------------------------
    init_kernel<<<(NN * HID + 255) / 256, 256, 0, stream>>>(acc, deg, NN);
    stats_kernel<<<(NN + 3) / 4, 256, 0, stream>>>(x, mu1, rs1, NN);
    int nT = R * HID * HID + HID * HID + FFD * HID + HID * FFD;
    transpose_kernel<<<(nT + 255) / 256, 256, 0, stream>>>(w, rootw, w1, w2,
                                                           WTw, rootT, W1T, W2T, R);
    ae_kernel<<<1, 64, 0, stream>>>(emb, att_edge, ae, R);
    deg_kernel<<<(E + 255) / 256, 256, 0, stream>>>(ei, deg, E, NN);
    scan1_kernel<<<nbScan, SCAN_B, 0, stream>>>(deg, offs, bsum, NN);
    scan2_kernel<<<1, SCAN_B, 0, stream>>>(bsum, nbScan);
    scan3_kernel<<<nbScan, SCAN_B, 0, stream>>>(offs, curpos, bsum, NN, nbScan);
    fill_kernel<<<(E + 255) / 256, 256, 0, stream>>>(ei, et, curpos, rs_arr, E, NN);

    // ---- phase 1: per-relation dots tables --------------------------------
    int gxN = (NN + 63) / 64;
    for (int rc = 0; rc < RR; rc++) {
        gemm_kernel<0, 0><<<dim3(gxN, HID / 64), 256, 0, stream>>>(
            x, mu1, rs1, n1w, n1b, WTw + (size_t)rc * HID * HID, x_chunk,
            nullptr, nullptr, nullptr, NN, HID, HID, 0, 0);
        dots_kernel<<<(NN * NH + 255) / 256, 256, 0, stream>>>(
            x_chunk, att_src, att_dst,
            as_all + (size_t)rc * NN * NH, ad_all + (size_t)rc * NN * NH, NN);
    }

    // ---- phase 2: exact per-edge softmax weights --------------------------
    wgt_kernel<<<(NN * NH + 255) / 256, 256, 0, stream>>>(
        offs, rs_arr, as_all, ad_all, ae, wgt, NN, E);

    // ---- phase 3: per-relation message accumulation -----------------------
    for (int rc = 0; rc < RR; rc++) {
        gemm_kernel<0, 0><<<dim3(gxN, HID / 64), 256, 0, stream>>>(
            x, mu1, rs1, n1w, n1b, WTw + (size_t)rc * HID * HID, x_chunk,
            nullptr, nullptr, nullptr, NN, HID, HID, 0, 0);
        msg2_kernel<<<NN, HID, 0, stream>>>(offs, rs_arr, wgt, x_chunk, acc, rc, NN, E);
    }

    // ---- phase 4: root gemm + msg + bias + elu + residual -> x2 (fp32, d_out)
    gemm_kernel<0, 1><<<dim3(gxN, HID / 64), 256, 0, stream>>>(
        x, mu1, rs1, n1w, n1b, rootT, x2, bias, acc, x, NN, HID, HID, 0, 0);

    // ---- phase 5: ln2 stats + FFN (row-chunked, u aliases x_chunk) --------
    stats_kernel<<<(NN + 3) / 4, 256, 0, stream>>>(x2, mu2, rs2, NN);
    int NCH = (NN + 3) / 4;
    for (int j = 0; j < 4; j++) {
        int r0 = j * NCH;
        int Mc = NN - r0; if (Mc > NCH) Mc = NCH;
        if (Mc <= 0) continue;
        int gxc = (Mc + 63) / 64;
        gemm_kernel<0, 2><<<dim3(gxc, FFD / 64), 256, 0, stream>>>(
            x2, mu2, rs2, n2w, n2b, W1T, u_ch, b1, nullptr, nullptr,
            Mc, FFD, HID, r0, 0);
        gemm_kernel<2, 3><<<dim3(gxc, HID / 64), 256, 0, stream>>>(
            u_ch, nullptr, nullptr, nullptr, nullptr, W2T, (float*)d_out, b2,
            nullptr, x2, Mc, HID, FFD, 0, r0);
    }
}